// Round 6
// baseline (193.469 us; speedup 1.0000x reference)
//
#include <hip/hip_runtime.h>

typedef unsigned short u16;
typedef unsigned int   u32;
typedef __attribute__((ext_vector_type(8))) short short8;   // 8 bf16
typedef __attribute__((ext_vector_type(4))) float f32x4;

__device__ __forceinline__ u16 f2bf(float f) {
    union { float f; u32 i; } v; v.f = f;
    u32 x = v.i;
    return (u16)((x + 0x7fffu + ((x >> 16) & 1u)) >> 16);   // RNE
}
__device__ __forceinline__ float bf2f(u16 u) {
    union { u32 i; float f; } v; v.i = ((u32)u) << 16; return v.f;
}

// ============================================================
// K1 [R3-exact revert — best measured config]: blocks [0,1024):
// conv, one image per block, stages the 29 needed rows as float4;
// padded LDS rows (stride 100 ≡ 12 mod 32 banks).
// blocks [1024,1824): one 32x32 ft_w transpose+split tile.
// (R5 isolated the 2-blocks-per-image split: +1.8us — reverted.)
// ============================================================
__global__ __launch_bounds__(256) void k1_fused(
    const float* __restrict__ images,   // (1024,3,96,96)
    const float* __restrict__ conv_w,   // (8,3,3,3)
    const float* __restrict__ ft_w,     // (800,1024)
    u16* __restrict__ vh, u16* __restrict__ vl,     // (1024,800)
    u16* __restrict__ bth, u16* __restrict__ btl)   // (1024,800) n-major
{
    __shared__ float img_s[3][29][100];   // padded (row stride 400B, 16B-aligned)
    __shared__ float w[216];
    __shared__ float tile[32][33];

    int t = threadIdx.x;

    if (blockIdx.x >= 1024) {
        int bid = blockIdx.x - 1024;       // 0..799
        int kb = bid / 32, nb = bid - kb * 32;
        int k0 = kb * 32, n0 = nb * 32;
        int tx = t & 31, ty = t >> 5;      // ty 0..7
        #pragma unroll
        for (int i = 0; i < 4; i++) {
            int k = ty + i * 8;
            tile[k][tx] = ft_w[(k0 + k) * 1024 + n0 + tx];
        }
        __syncthreads();
        #pragma unroll
        for (int i = 0; i < 4; i++) {
            int n = ty + i * 8;
            float wv = tile[tx][n];
            u16 hi = f2bf(wv);
            float lo = wv - bf2f(hi);
            bth[(n0 + n) * 800 + k0 + tx] = hi;
            btl[(n0 + n) * 800 + k0 + tx] = f2bf(lo);
        }
        return;
    }

    int b = blockIdx.x;
    if (t < 216) w[t] = conv_w[t];

    // float4 image staging: 3*29*24 = 2088 vec4 elements
    for (int i = t; i < 3 * 29 * 24; i += 256) {
        int ch  = i / (29 * 24);
        int rem = i - ch * (29 * 24);
        int lr  = rem / 24;
        int x4  = rem - lr * 24;
        int ih  = 10 * ((lr + 1) / 3) + (lr + 1) % 3 - 1;
        *(float4*)&img_s[ch][lr][x4 * 4] =
            *(const float4*)&images[((b * 3 + ch) * 96 + ih) * 96 + x4 * 4];
    }
    __syncthreads();

    for (int ridx = t; ridx < 800; ridx += 256) {
        int o  = ridx / 100;
        int p  = ridx - o * 100;
        int oh = p / 10;
        int ow = p - oh * 10;

        float sum = 0.0f;
        #pragma unroll
        for (int ic = 0; ic < 3; ic++) {
            const float* wc = &w[o * 27 + ic * 9];
            #pragma unroll
            for (int kh = 0; kh < 3; kh++) {
                int lr = 3 * oh + kh - 1;
                if (lr < 0) continue;
                #pragma unroll
                for (int kw = 0; kw < 3; kw++) {
                    int iw = ow * 10 + kw - 1;
                    if (iw < 0) continue;
                    sum = fmaf(img_s[ic][lr][iw], wc[kh * 3 + kw], sum);
                }
            }
        }
        float xc = fminf(fmaxf(sum, -1.0f), 1.0f);
        float binary = 1.0f / (1.0f + __expf(-10.0f * xc));
        float v = (binary > 0.5f) ? binary : 0.0f;
        u16 hi = f2bf(v);
        vh[b * 800 + ridx] = hi;
        vl[b * 800 + ridx] = f2bf(v - bf2f(hi));
    }
}

// ============================================================
// K2: split-bf16 MFMA GEMM, 64x64 tile, 4 waves, 2x2 frags,
// register-prefetch pipelining, split-K x2 via blockIdx.z
// (k in [0,416) / [416,800)) -> 512 blocks = 2 INDEPENDENT
// blocks/CU (independent barrier domains overlap stalls; R4's
// in-block split-K fused them and regressed).
// Partials written RAW to two f32 buffers; K3 reduces.
// [R3-validated form]
// ============================================================
__global__ __launch_bounds__(256) void k2_mfma(
    const u16* __restrict__ Ah, const u16* __restrict__ Al,   // (1024,800)
    const u16* __restrict__ Bh, const u16* __restrict__ Bl,   // (1024,800) n-major
    float* __restrict__ C0, float* __restrict__ C1)           // (1024,1024) partials
{
    __shared__ u16 sAh[64 * 40], sAl[64 * 40], sBh[64 * 40], sBl[64 * 40];
    int t = threadIdx.x;
    int m0 = blockIdx.y * 64, n0 = blockIdx.x * 64;
    int kb = (blockIdx.z == 0) ? 0 : 416;
    int ke = (blockIdx.z == 0) ? 416 : 800;
    float* C = (blockIdx.z == 0) ? C0 : C1;

    int w = t >> 6, lane = t & 63;
    int quad = lane >> 4, lo4 = lane & 15;
    int wm = (w >> 1) * 32, wn = (w & 1) * 32;

    int sr = t >> 2;   // staging row 0..63
    int sq = t & 3;    // 8-elem chunk 0..3
    const u16* gAh = Ah + (m0 + sr) * 800 + sq * 8;
    const u16* gAl = Al + (m0 + sr) * 800 + sq * 8;
    const u16* gBh = Bh + (n0 + sr) * 800 + sq * 8;
    const u16* gBl = Bl + (n0 + sr) * 800 + sq * 8;
    int sdst = sr * 40 + sq * 8;

    f32x4 acc[2][2] = {};

    uint4 rAh = *(const uint4*)(gAh + kb);
    uint4 rAl = *(const uint4*)(gAl + kb);
    uint4 rBh = *(const uint4*)(gBh + kb);
    uint4 rBl = *(const uint4*)(gBl + kb);

    for (int k0 = kb; k0 < ke; k0 += 32) {
        *(uint4*)&sAh[sdst] = rAh;
        *(uint4*)&sAl[sdst] = rAl;
        *(uint4*)&sBh[sdst] = rBh;
        *(uint4*)&sBl[sdst] = rBl;
        __syncthreads();

        if (k0 + 32 < ke) {                // prefetch next tile
            rAh = *(const uint4*)(gAh + k0 + 32);
            rAl = *(const uint4*)(gAl + k0 + 32);
            rBh = *(const uint4*)(gBh + k0 + 32);
            rBl = *(const uint4*)(gBl + k0 + 32);
        }

        short8 a_h[2], a_l[2], b_h[2], b_l[2];
        #pragma unroll
        for (int f = 0; f < 2; f++) {
            int mi = (wm + f * 16 + lo4) * 40 + quad * 8;
            a_h[f] = *(const short8*)&sAh[mi];
            a_l[f] = *(const short8*)&sAl[mi];
            int ni = (wn + f * 16 + lo4) * 40 + quad * 8;
            b_h[f] = *(const short8*)&sBh[ni];
            b_l[f] = *(const short8*)&sBl[ni];
        }
        #pragma unroll
        for (int fm = 0; fm < 2; fm++)
            #pragma unroll
            for (int fn = 0; fn < 2; fn++) {
                acc[fm][fn] = __builtin_amdgcn_mfma_f32_16x16x32_bf16(a_h[fm], b_h[fn], acc[fm][fn], 0, 0, 0);
                acc[fm][fn] = __builtin_amdgcn_mfma_f32_16x16x32_bf16(a_h[fm], b_l[fn], acc[fm][fn], 0, 0, 0);
                acc[fm][fn] = __builtin_amdgcn_mfma_f32_16x16x32_bf16(a_l[fm], b_h[fn], acc[fm][fn], 0, 0, 0);
            }
        __syncthreads();
    }

    // C/D layout: col = lane&15, row = quad*4 + reg.  Raw partial store.
    #pragma unroll
    for (int fm = 0; fm < 2; fm++) {
        #pragma unroll
        for (int fn = 0; fn < 2; fn++) {
            int n = n0 + wn + fn * 16 + lo4;
            #pragma unroll
            for (int r = 0; r < 4; r++) {
                int m = m0 + wm + fm * 16 + quad * 4 + r;
                C[m * 1024 + n] = acc[fm][fn][r];
            }
        }
    }
}

// ============================================================
// K3: THIS ROUND — one row per block, 4 waves = (k-half, j-half):
// wave = jh*2 + half; half picks pair-chunks 0..63 / 64..127,
// jh picks j 0..7 / 8..14.  Per-lane float4 issue count 36 -> 22
// (w1 rows were the dominant serial chain: 30 -> 14/16); 1024
// blocks = 4 blocks/CU (was 2).  h1 sum (acc_h0 + acc_h1) + b1
// keeps R3's FP association exactly -> bit-identical output.
// ============================================================
__global__ __launch_bounds__(256) void k3_tail(
    const float* __restrict__ l0a, // (1024,1024) partial 0
    const float* __restrict__ l0b, // (1024,1024) partial 1
    const float* __restrict__ ft_b,// (1024,)
    const float* __restrict__ w1,  // (15,1024)
    const float* __restrict__ b1,
    const float* __restrict__ w2,  // (32,15)
    const float* __restrict__ b2,
    const float* __restrict__ w3,  // (1,32)
    const float* __restrict__ b3,
    float* __restrict__ out)       // (1024,)
{
    __shared__ float red[2][2][8]; // [jh][half][j-idx]

    int wave = threadIdx.x >> 6;   // 0..3
    int lane = threadIdx.x & 63;
    int half = wave & 1;           // k-half: pair-chunks 0..63 / 64..127
    int jh   = wave >> 1;          // j-half: j 0..7 / 8..14
    int jbeg = jh * 8;
    int jcnt = jh ? 7 : 8;
    int b = blockIdx.x;
    const float* pa = l0a + b * 1024;
    const float* pb = l0b + b * 1024;
    const float cc = 0.9921875f;   // 127/128

    float acc[8];
    #pragma unroll
    for (int j = 0; j < 8; j++) acc[j] = 0.f;

    {
        int k4 = (lane + half * 64) * 4;         // this wave's 64 chunks
        float4 a0 = *(const float4*)(pa + k4);
        float4 q0 = *(const float4*)(pb + k4);
        float4 f0 = *(const float4*)(ft_b + k4);
        float4 a1 = *(const float4*)(pa + k4 + 512);
        float4 q1 = *(const float4*)(pb + k4 + 512);
        float4 f1 = *(const float4*)(ft_b + k4 + 512);
        float4 x0, x1;
        x0.x = fminf(fmaxf(a0.x + q0.x + f0.x, 0.f), 1.f);
        x0.y = fminf(fmaxf(a0.y + q0.y + f0.y, 0.f), 1.f);
        x0.z = fminf(fmaxf(a0.z + q0.z + f0.z, 0.f), 1.f);
        x0.w = fminf(fmaxf(a0.w + q0.w + f0.w, 0.f), 1.f);
        x1.x = fminf(fmaxf(a1.x + q1.x + f1.x, 0.f), 1.f);
        x1.y = fminf(fmaxf(a1.y + q1.y + f1.y, 0.f), 1.f);
        x1.z = fminf(fmaxf(a1.z + q1.z + f1.z, 0.f), 1.f);
        x1.w = fminf(fmaxf(a1.w + q1.w + f1.w, 0.f), 1.f);

        float4 va, vb;
        va.x = x0.x * x1.x * cc; va.y = x0.y * x1.y * cc;
        va.z = x0.z * x1.z * cc; va.w = x0.w * x1.w * cc;
        vb.x = x0.x * cc; vb.y = x0.y * cc;
        vb.z = x0.z * cc; vb.w = x0.w * cc;
        for (int jj = 0; jj < jcnt; jj++) {
            int j = jbeg + jj;
            float4 wa = *(const float4*)(w1 + j * 1024 + k4);
            float4 wb = *(const float4*)(w1 + j * 1024 + k4 + 512);
            float s = acc[jj];
            s = fmaf(va.x, wa.x, s); s = fmaf(va.y, wa.y, s);
            s = fmaf(va.z, wa.z, s); s = fmaf(va.w, wa.w, s);
            s = fmaf(vb.x, wb.x, s); s = fmaf(vb.y, wb.y, s);
            s = fmaf(vb.z, wb.z, s); s = fmaf(vb.w, wb.w, s);
            acc[jj] = s;
        }
    }

    #pragma unroll
    for (int jj = 0; jj < 8; jj++) {
        #pragma unroll
        for (int m = 32; m >= 1; m >>= 1)
            acc[jj] += __shfl_xor(acc[jj], m, 64);
    }

    if (lane == 0) {
        for (int jj = 0; jj < jcnt; jj++) red[jh][half][jj] = acc[jj];
    }
    __syncthreads();

    if (wave == 0) {
        float h1[15];
        #pragma unroll
        for (int j = 0; j < 15; j++) {
            int jhh = j >> 3, jj = j & 7;
            // (half0 + half1) + b1 — same association as R3's acc+red+b1
            h1[j] = fmaxf(red[jhh][0][jj] + red[jhh][1][jj] + b1[j], 0.f);
        }

        float contrib = 0.f;
        if (lane < 32) {
            float h2 = b2[lane];
            #pragma unroll
            for (int j = 0; j < 15; j++) h2 = fmaf(h1[j], w2[lane * 15 + j], h2);
            h2 = fmaxf(h2, 0.f);
            contrib = h2 * w3[lane];
        }
        #pragma unroll
        for (int m = 32; m >= 1; m >>= 1) contrib += __shfl_xor(contrib, m, 64);

        if (lane == 0) out[b] = contrib + b3[0];
    }
}

// ============================================================
extern "C" void kernel_launch(void* const* d_in, const int* in_sizes, int n_in,
                              void* d_out, int out_size, void* d_ws, size_t ws_size,
                              hipStream_t stream) {
    const float* images = (const float*)d_in[0];
    const float* conv_w = (const float*)d_in[1];
    const float* ft_w   = (const float*)d_in[2];
    const float* ft_b   = (const float*)d_in[3];
    const float* w1     = (const float*)d_in[4];
    const float* b1     = (const float*)d_in[5];
    const float* w2     = (const float*)d_in[6];
    const float* b2     = (const float*)d_in[7];
    const float* w3     = (const float*)d_in[8];
    const float* b3     = (const float*)d_in[9];
    float* out = (float*)d_out;

    const int NV = 1024 * 800;                 // 819200
    u16* vh  = (u16*)d_ws;
    u16* vl  = vh + NV;
    u16* bth = vl + NV;
    u16* btl = bth + NV;
    float* l0a = (float*)(btl + NV);           // (1024,1024) f32 partial 0
    float* l0b = l0a + 1024 * 1024;            // (1024,1024) f32 partial 1

    k1_fused<<<1824, 256, 0, stream>>>(images, conv_w, ft_w, vh, vl, bth, btl);
    k2_mfma<<<dim3(16, 16, 2), 256, 0, stream>>>(vh, vl, bth, btl, l0a, l0b);
    k3_tail<<<1024, 256, 0, stream>>>(l0a, l0b, ft_b, w1, b1, w2, b2, w3, b3, out);
}

// Round 7
// 191.776 us; speedup vs baseline: 1.0088x; 1.0088x over previous
//
#include <hip/hip_runtime.h>

typedef unsigned short u16;
typedef unsigned int   u32;
typedef __attribute__((ext_vector_type(8))) short short8;   // 8 bf16
typedef __attribute__((ext_vector_type(4))) float f32x4;

__device__ __forceinline__ u16 f2bf(float f) {
    union { float f; u32 i; } v; v.f = f;
    u32 x = v.i;
    return (u16)((x + 0x7fffu + ((x >> 16) & 1u)) >> 16);   // RNE
}
__device__ __forceinline__ float bf2f(u16 u) {
    union { u32 i; float f; } v; v.i = ((u32)u) << 16; return v.f;
}

// ============================================================
// R3-EXACT CONFIGURATION — best measured (190.6 us).  Every
// component adjudicated in isolation across R4-R6:
//   K1 1-image/block + f4 staging (2-block split: −1.8us, R5)
//   K2 cross-block split-K x2     (in-block split-K: −3.6us, R4)
//   K3 2-wave/row                 (4-wave j-split: −2.9us, R6)
// ============================================================

// K1: blocks [0,1024): conv, one image per block; stages 29 rows
// as float4; padded LDS rows (stride 100 ≡ 12 mod 32 banks).
// blocks [1024,1824): one 32x32 ft_w transpose+split tile.
__global__ __launch_bounds__(256) void k1_fused(
    const float* __restrict__ images,   // (1024,3,96,96)
    const float* __restrict__ conv_w,   // (8,3,3,3)
    const float* __restrict__ ft_w,     // (800,1024)
    u16* __restrict__ vh, u16* __restrict__ vl,     // (1024,800)
    u16* __restrict__ bth, u16* __restrict__ btl)   // (1024,800) n-major
{
    __shared__ float img_s[3][29][100];   // padded (row stride 400B, 16B-aligned)
    __shared__ float w[216];
    __shared__ float tile[32][33];

    int t = threadIdx.x;

    if (blockIdx.x >= 1024) {
        int bid = blockIdx.x - 1024;       // 0..799
        int kb = bid / 32, nb = bid - kb * 32;
        int k0 = kb * 32, n0 = nb * 32;
        int tx = t & 31, ty = t >> 5;      // ty 0..7
        #pragma unroll
        for (int i = 0; i < 4; i++) {
            int k = ty + i * 8;
            tile[k][tx] = ft_w[(k0 + k) * 1024 + n0 + tx];
        }
        __syncthreads();
        #pragma unroll
        for (int i = 0; i < 4; i++) {
            int n = ty + i * 8;
            float wv = tile[tx][n];
            u16 hi = f2bf(wv);
            float lo = wv - bf2f(hi);
            bth[(n0 + n) * 800 + k0 + tx] = hi;
            btl[(n0 + n) * 800 + k0 + tx] = f2bf(lo);
        }
        return;
    }

    int b = blockIdx.x;
    if (t < 216) w[t] = conv_w[t];

    // float4 image staging: 3*29*24 = 2088 vec4 elements
    for (int i = t; i < 3 * 29 * 24; i += 256) {
        int ch  = i / (29 * 24);
        int rem = i - ch * (29 * 24);
        int lr  = rem / 24;
        int x4  = rem - lr * 24;
        int ih  = 10 * ((lr + 1) / 3) + (lr + 1) % 3 - 1;
        *(float4*)&img_s[ch][lr][x4 * 4] =
            *(const float4*)&images[((b * 3 + ch) * 96 + ih) * 96 + x4 * 4];
    }
    __syncthreads();

    for (int ridx = t; ridx < 800; ridx += 256) {
        int o  = ridx / 100;
        int p  = ridx - o * 100;
        int oh = p / 10;
        int ow = p - oh * 10;

        float sum = 0.0f;
        #pragma unroll
        for (int ic = 0; ic < 3; ic++) {
            const float* wc = &w[o * 27 + ic * 9];
            #pragma unroll
            for (int kh = 0; kh < 3; kh++) {
                int lr = 3 * oh + kh - 1;
                if (lr < 0) continue;
                #pragma unroll
                for (int kw = 0; kw < 3; kw++) {
                    int iw = ow * 10 + kw - 1;
                    if (iw < 0) continue;
                    sum = fmaf(img_s[ic][lr][iw], wc[kh * 3 + kw], sum);
                }
            }
        }
        float xc = fminf(fmaxf(sum, -1.0f), 1.0f);
        float binary = 1.0f / (1.0f + __expf(-10.0f * xc));
        float v = (binary > 0.5f) ? binary : 0.0f;
        u16 hi = f2bf(v);
        vh[b * 800 + ridx] = hi;
        vl[b * 800 + ridx] = f2bf(v - bf2f(hi));
    }
}

// K2: split-bf16 MFMA GEMM, 64x64 tile, 4 waves, 2x2 frags,
// register-prefetch pipelining, split-K x2 via blockIdx.z
// (k in [0,416) / [416,800)) -> 512 blocks = 2 INDEPENDENT
// blocks/CU.  Partials written RAW to two f32 buffers; K3 reduces.
__global__ __launch_bounds__(256) void k2_mfma(
    const u16* __restrict__ Ah, const u16* __restrict__ Al,   // (1024,800)
    const u16* __restrict__ Bh, const u16* __restrict__ Bl,   // (1024,800) n-major
    float* __restrict__ C0, float* __restrict__ C1)           // (1024,1024) partials
{
    __shared__ u16 sAh[64 * 40], sAl[64 * 40], sBh[64 * 40], sBl[64 * 40];
    int t = threadIdx.x;
    int m0 = blockIdx.y * 64, n0 = blockIdx.x * 64;
    int kb = (blockIdx.z == 0) ? 0 : 416;
    int ke = (blockIdx.z == 0) ? 416 : 800;
    float* C = (blockIdx.z == 0) ? C0 : C1;

    int w = t >> 6, lane = t & 63;
    int quad = lane >> 4, lo4 = lane & 15;
    int wm = (w >> 1) * 32, wn = (w & 1) * 32;

    int sr = t >> 2;   // staging row 0..63
    int sq = t & 3;    // 8-elem chunk 0..3
    const u16* gAh = Ah + (m0 + sr) * 800 + sq * 8;
    const u16* gAl = Al + (m0 + sr) * 800 + sq * 8;
    const u16* gBh = Bh + (n0 + sr) * 800 + sq * 8;
    const u16* gBl = Bl + (n0 + sr) * 800 + sq * 8;
    int sdst = sr * 40 + sq * 8;

    f32x4 acc[2][2] = {};

    uint4 rAh = *(const uint4*)(gAh + kb);
    uint4 rAl = *(const uint4*)(gAl + kb);
    uint4 rBh = *(const uint4*)(gBh + kb);
    uint4 rBl = *(const uint4*)(gBl + kb);

    for (int k0 = kb; k0 < ke; k0 += 32) {
        *(uint4*)&sAh[sdst] = rAh;
        *(uint4*)&sAl[sdst] = rAl;
        *(uint4*)&sBh[sdst] = rBh;
        *(uint4*)&sBl[sdst] = rBl;
        __syncthreads();

        if (k0 + 32 < ke) {                // prefetch next tile
            rAh = *(const uint4*)(gAh + k0 + 32);
            rAl = *(const uint4*)(gAl + k0 + 32);
            rBh = *(const uint4*)(gBh + k0 + 32);
            rBl = *(const uint4*)(gBl + k0 + 32);
        }

        short8 a_h[2], a_l[2], b_h[2], b_l[2];
        #pragma unroll
        for (int f = 0; f < 2; f++) {
            int mi = (wm + f * 16 + lo4) * 40 + quad * 8;
            a_h[f] = *(const short8*)&sAh[mi];
            a_l[f] = *(const short8*)&sAl[mi];
            int ni = (wn + f * 16 + lo4) * 40 + quad * 8;
            b_h[f] = *(const short8*)&sBh[ni];
            b_l[f] = *(const short8*)&sBl[ni];
        }
        #pragma unroll
        for (int fm = 0; fm < 2; fm++)
            #pragma unroll
            for (int fn = 0; fn < 2; fn++) {
                acc[fm][fn] = __builtin_amdgcn_mfma_f32_16x16x32_bf16(a_h[fm], b_h[fn], acc[fm][fn], 0, 0, 0);
                acc[fm][fn] = __builtin_amdgcn_mfma_f32_16x16x32_bf16(a_h[fm], b_l[fn], acc[fm][fn], 0, 0, 0);
                acc[fm][fn] = __builtin_amdgcn_mfma_f32_16x16x32_bf16(a_l[fm], b_h[fn], acc[fm][fn], 0, 0, 0);
            }
        __syncthreads();
    }

    // C/D layout: col = lane&15, row = quad*4 + reg.  Raw partial store.
    #pragma unroll
    for (int fm = 0; fm < 2; fm++) {
        #pragma unroll
        for (int fn = 0; fn < 2; fn++) {
            int n = n0 + wn + fn * 16 + lo4;
            #pragma unroll
            for (int r = 0; r < 4; r++) {
                int m = m0 + wm + fm * 16 + quad * 4 + r;
                C[m * 1024 + n] = acc[fm][fn][r];
            }
        }
    }
}

// K3: per-row tail, 2 waves per row (pair-space chunks 0..63 /
// 64..127), LDS combine of the 15 partials, finish on the half==0
// wave.  Reduces the two split-K partials + ft_b + clip inline.
__global__ __launch_bounds__(256) void k3_tail(
    const float* __restrict__ l0a, // (1024,1024) partial 0
    const float* __restrict__ l0b, // (1024,1024) partial 1
    const float* __restrict__ ft_b,// (1024,)
    const float* __restrict__ w1,  // (15,1024)
    const float* __restrict__ b1,
    const float* __restrict__ w2,  // (32,15)
    const float* __restrict__ b2,
    const float* __restrict__ w3,  // (1,32)
    const float* __restrict__ b3,
    float* __restrict__ out)       // (1024,)
{
    __shared__ float red[2][15];   // [row][j], written by half==1 wave

    int wave = threadIdx.x >> 6;   // 0..3
    int lane = threadIdx.x & 63;
    int row  = wave >> 1;          // 0..1
    int half = wave & 1;           // 0..1
    int b = blockIdx.x * 2 + row;
    const float* pa = l0a + b * 1024;
    const float* pb = l0b + b * 1024;
    const float cc = 0.9921875f;   // 127/128

    float acc[15];
    #pragma unroll
    for (int j = 0; j < 15; j++) acc[j] = 0.f;

    {
        int k4 = (lane + half * 64) * 4;         // this wave's 64 chunks
        float4 a0 = *(const float4*)(pa + k4);
        float4 q0 = *(const float4*)(pb + k4);
        float4 f0 = *(const float4*)(ft_b + k4);
        float4 a1 = *(const float4*)(pa + k4 + 512);
        float4 q1 = *(const float4*)(pb + k4 + 512);
        float4 f1 = *(const float4*)(ft_b + k4 + 512);
        float4 x0, x1;
        x0.x = fminf(fmaxf(a0.x + q0.x + f0.x, 0.f), 1.f);
        x0.y = fminf(fmaxf(a0.y + q0.y + f0.y, 0.f), 1.f);
        x0.z = fminf(fmaxf(a0.z + q0.z + f0.z, 0.f), 1.f);
        x0.w = fminf(fmaxf(a0.w + q0.w + f0.w, 0.f), 1.f);
        x1.x = fminf(fmaxf(a1.x + q1.x + f1.x, 0.f), 1.f);
        x1.y = fminf(fmaxf(a1.y + q1.y + f1.y, 0.f), 1.f);
        x1.z = fminf(fmaxf(a1.z + q1.z + f1.z, 0.f), 1.f);
        x1.w = fminf(fmaxf(a1.w + q1.w + f1.w, 0.f), 1.f);

        float4 va, vb;
        va.x = x0.x * x1.x * cc; va.y = x0.y * x1.y * cc;
        va.z = x0.z * x1.z * cc; va.w = x0.w * x1.w * cc;
        vb.x = x0.x * cc; vb.y = x0.y * cc;
        vb.z = x0.z * cc; vb.w = x0.w * cc;
        #pragma unroll
        for (int j = 0; j < 15; j++) {
            float4 wa = *(const float4*)(w1 + j * 1024 + k4);
            float4 wb = *(const float4*)(w1 + j * 1024 + k4 + 512);
            acc[j] = fmaf(va.x, wa.x, acc[j]); acc[j] = fmaf(va.y, wa.y, acc[j]);
            acc[j] = fmaf(va.z, wa.z, acc[j]); acc[j] = fmaf(va.w, wa.w, acc[j]);
            acc[j] = fmaf(vb.x, wb.x, acc[j]); acc[j] = fmaf(vb.y, wb.y, acc[j]);
            acc[j] = fmaf(vb.z, wb.z, acc[j]); acc[j] = fmaf(vb.w, wb.w, acc[j]);
        }
    }

    #pragma unroll
    for (int j = 0; j < 15; j++) {
        #pragma unroll
        for (int m = 32; m >= 1; m >>= 1)
            acc[j] += __shfl_xor(acc[j], m, 64);
    }

    if (half == 1 && lane == 0) {
        #pragma unroll
        for (int j = 0; j < 15; j++) red[row][j] = acc[j];
    }
    __syncthreads();

    if (half == 0) {
        float h1[15];
        #pragma unroll
        for (int j = 0; j < 15; j++)
            h1[j] = fmaxf(acc[j] + red[row][j] + b1[j], 0.f);

        float contrib = 0.f;
        if (lane < 32) {
            float h2 = b2[lane];
            #pragma unroll
            for (int j = 0; j < 15; j++) h2 = fmaf(h1[j], w2[lane * 15 + j], h2);
            h2 = fmaxf(h2, 0.f);
            contrib = h2 * w3[lane];
        }
        #pragma unroll
        for (int m = 32; m >= 1; m >>= 1) contrib += __shfl_xor(contrib, m, 64);

        if (lane == 0) out[b] = contrib + b3[0];
    }
}

// ============================================================
extern "C" void kernel_launch(void* const* d_in, const int* in_sizes, int n_in,
                              void* d_out, int out_size, void* d_ws, size_t ws_size,
                              hipStream_t stream) {
    const float* images = (const float*)d_in[0];
    const float* conv_w = (const float*)d_in[1];
    const float* ft_w   = (const float*)d_in[2];
    const float* ft_b   = (const float*)d_in[3];
    const float* w1     = (const float*)d_in[4];
    const float* b1     = (const float*)d_in[5];
    const float* w2     = (const float*)d_in[6];
    const float* b2     = (const float*)d_in[7];
    const float* w3     = (const float*)d_in[8];
    const float* b3     = (const float*)d_in[9];
    float* out = (float*)d_out;

    const int NV = 1024 * 800;                 // 819200
    u16* vh  = (u16*)d_ws;
    u16* vl  = vh + NV;
    u16* bth = vl + NV;
    u16* btl = bth + NV;
    float* l0a = (float*)(btl + NV);           // (1024,1024) f32 partial 0
    float* l0b = l0a + 1024 * 1024;            // (1024,1024) f32 partial 1

    k1_fused<<<1824, 256, 0, stream>>>(images, conv_w, ft_w, vh, vl, bth, btl);
    k2_mfma<<<dim3(16, 16, 2), 256, 0, stream>>>(vh, vl, bth, btl, l0a, l0b);
    k3_tail<<<512, 256, 0, stream>>>(l0a, l0b, ft_b, w1, b1, w2, b2, w3, b3, out);
}